// Round 4
// baseline (2049.366 us; speedup 1.0000x reference)
//
#include <hip/hip_runtime.h>
#include <hip/hip_bf16.h>

#define NN 20000
#define TT 16
#define EE 320000
#define CC 128
#define HH 128
#define PP 100000
#define QN (NN / 4)   // node groups of 4 for agg

typedef float  f32x4  __attribute__((ext_vector_type(4)));
typedef unsigned short ushort8v __attribute__((ext_vector_type(8)));
typedef unsigned u32x4 __attribute__((ext_vector_type(4)));
typedef _Float16 h2v __attribute__((ext_vector_type(2)));
typedef _Float16 h4v __attribute__((ext_vector_type(4)));
typedef _Float16 f16x8 __attribute__((ext_vector_type(8)));

union pk16 { unsigned u; _Float16 h[2]; };

// ---------------- batched CSR build, XCD-pinned: frame = blockIdx.x % 16 ----------------

__global__ void hist_all_k(const int* __restrict__ edge_index, int* __restrict__ cnt_all) {
    int b = blockIdx.x;
    int f = b & 15, chunk = b >> 4;
    const int* dst = edge_index + (size_t)f * 2 * EE + EE;
    int* cnt = cnt_all + f * NN;
    int base = chunk * 1024 + threadIdx.x;
#pragma unroll
    for (int i = 0; i < 4; ++i) {
        int e = base + i * 256;
        if (e < EE) {
            int d = __builtin_nontemporal_load(dst + e);
            atomicAdd(&cnt[d], 1);
        }
    }
}

__global__ __launch_bounds__(1024) void scan_all_k(const int* __restrict__ cnt_all,
                                                   int* __restrict__ offs_all,
                                                   float* __restrict__ dinv_all,
                                                   int* __restrict__ cursor_all) {
    __shared__ int part[1024];
    int f = blockIdx.x;
    const int* cnt = cnt_all + f * NN;
    int* offs = offs_all + f * (NN + 1);
    int t = threadIdx.x;
    int base = t * 20;
    int vals[20];
    int s = 0;
#pragma unroll
    for (int i = 0; i < 20; ++i) {
        int idx = base + i;
        int v = (idx < NN) ? cnt[idx] : 0;
        vals[i] = v; s += v;
    }
    part[t] = s;
    __syncthreads();
    for (int off = 1; off < 1024; off <<= 1) {
        int v = (t >= off) ? part[t - off] : 0;
        __syncthreads();
        part[t] += v;
        __syncthreads();
    }
    int run = part[t] - s;
#pragma unroll
    for (int i = 0; i < 20; ++i) {
        int idx = base + i;
        if (idx < NN) {
            offs[idx] = run;
            cursor_all[f * NN + idx] = f * EE + run;
            dinv_all[f * NN + idx] = rsqrtf((float)vals[i] + 1.0f);
            run += vals[i];
        }
    }
    if (t == 0) offs[NN] = EE;
}

__global__ void fill_all_k(const int* __restrict__ edge_index,
                           int* __restrict__ cursor_all,
                           unsigned short* __restrict__ csr_all) {
    int b = blockIdx.x;
    int f = b & 15, chunk = b >> 4;
    const int* src = edge_index + (size_t)f * 2 * EE;
    const int* dst = src + EE;
    int* cur = cursor_all + f * NN;
    int base = chunk * 1024 + threadIdx.x;
#pragma unroll
    for (int i = 0; i < 4; ++i) {
        int e = base + i * 256;
        if (e < EE) {
            int d = __builtin_nontemporal_load(dst + e);
            int s = __builtin_nontemporal_load(src + e);
            int pos = atomicAdd(&cur[d], 1);
            csr_all[pos] = (unsigned short)s;
        }
    }
}

// ---------------- weight prep: fp32 -> fp16 high + fp16 residual (22-bit coverage) ----------------
__global__ void wprep_t_k(const float* __restrict__ W,
                          _Float16* __restrict__ oh,
                          _Float16* __restrict__ ol) {
    int i = blockIdx.x * blockDim.x + threadIdx.x;
    if (i >= 128 * 128) return;
    int n = i >> 7, k = i & 127;
    float v = W[k * 128 + n];
    _Float16 h = (_Float16)v;
    oh[i] = h;
    ol[i] = (_Float16)(v - (float)h);
}

__global__ void wprep_d_k(const float* __restrict__ w,
                          _Float16* __restrict__ oh,
                          _Float16* __restrict__ ol, int n) {
    int i = blockIdx.x * blockDim.x + threadIdx.x;
    if (i >= n) return;
    float v = w[i];
    _Float16 h = (_Float16)v;
    oh[i] = h;
    ol[i] = (_Float16)(v - (float)h);
}

// ---------------- g0 = dinv ⊙ x  (fp32 -> fp16) ----------------
__global__ __launch_bounds__(256) void scale_k(const float* __restrict__ x,
                                               const float* __restrict__ dinv_all,
                                               _Float16* __restrict__ g) {
    int idx = blockIdx.x * blockDim.x + threadIdx.x;
    int row = idx >> 5, q = idx & 31;
    const f32x4* xp = (const f32x4*)(x + (size_t)row * 128 + q * 4);
    f32x4 v = __builtin_nontemporal_load(xp);
    float d = dinv_all[row];
    h4v o;
    o.x = (_Float16)(v.x * d); o.y = (_Float16)(v.y * d);
    o.z = (_Float16)(v.z * d); o.w = (_Float16)(v.w * d);
    *(h4v*)(g + (size_t)row * 128 + q * 4) = o;
}

// ---------------- aggregation, feature-halved + XCD-pinned ----------------
__global__ __launch_bounds__(128) void agg_half_k(const _Float16* __restrict__ g,
                                                  const unsigned short* __restrict__ csr_all,
                                                  const int* __restrict__ offs_all,
                                                  _Float16* __restrict__ a) {
    int b = blockIdx.x;
    int xcd = b & 7;
    int r1 = b >> 3;
    int grp = r1 % QN;
    int pass = r1 / QN;                 // 0..3, slowest
    int f = xcd + ((pass & 1) << 3);    // frame octet
    int hoff = (pass >> 1) * 64;        // feature half
    int t = threadIdx.x;
    int node = grp * 4 + (t >> 5);
    int lane = t & 31;
    const int* offs = offs_all + f * (NN + 1);
    const unsigned short* csr = csr_all + (size_t)f * EE;
    const _Float16* gf = g + (size_t)f * NN * HH + hoff + lane * 2;
    int beg = offs[node], end = offs[node + 1];
    float a0 = 0.f, a1 = 0.f;
    int e = beg;
    for (; e + 3 < end; e += 4) {
        int s0 = csr[e], s1 = csr[e + 1], s2 = csr[e + 2], s3 = csr[e + 3];
        h2v v0 = *(const h2v*)(gf + (size_t)s0 * HH);
        h2v v1 = *(const h2v*)(gf + (size_t)s1 * HH);
        h2v v2 = *(const h2v*)(gf + (size_t)s2 * HH);
        h2v v3 = *(const h2v*)(gf + (size_t)s3 * HH);
        a0 += ((float)v0.x + (float)v1.x) + ((float)v2.x + (float)v3.x);
        a1 += ((float)v0.y + (float)v1.y) + ((float)v2.y + (float)v3.y);
    }
    for (; e < end; ++e) {
        h2v v = *(const h2v*)(gf + (size_t)csr[e] * HH);
        a0 += (float)v.x; a1 += (float)v.y;
    }
    h2v vs = *(const h2v*)(gf + (size_t)node * HH);
    a0 += (float)vs.x; a1 += (float)vs.y;
    h2v r; r.x = (_Float16)a0; r.y = (_Float16)a1;
    *(h2v*)(a + ((size_t)f * NN + node) * HH + hoff + lane * 2) = r;
}

// ---------------- fp16 MFMA GEMM, XCD-bijective swizzle ----------------
__global__ __launch_bounds__(256) void gemm_f16(const _Float16* __restrict__ A,
                                                const _Float16* __restrict__ Bh,
                                                const _Float16* __restrict__ Bl,
                                                _Float16* __restrict__ out,
                                                const float* __restrict__ rowscale,
                                                const float* __restrict__ bias,
                                                int M, int NC, int relu, int postscale) {
    __shared__ _Float16 As[64 * 72], Bhs[64 * 72], Bls[64 * 72];
    int t = threadIdx.x;
    int b = blockIdx.x;
    int xcd = b & 7, k = b >> 3;
    int row_t = xcd + ((k >> 1) << 3);     // M/64 = 5000 = 8*625, bijective
    int col_t = k & 1;
    int row0 = row_t * 64, col0 = col_t * 64;
    int w = t >> 6, lane = t & 63;
    int wm = (w & 1) * 32, wn = (w >> 1) * 32;
    int lm = lane & 15, lq = lane >> 4;
    f32x4 acc[2][2] = {};

    for (int ks = 0; ks < 2; ++ks) {
        if (ks) __syncthreads();
#pragma unroll
        for (int p = 0; p < 2; ++p) {
            int s = t + p * 256;
            int r = s >> 3, c8 = s & 7;
            int gr = row0 + r;
            ushort8v va = {};
            if (gr < M)
                va = *(const ushort8v*)(A + (size_t)gr * 128 + ks * 64 + c8 * 8);
            *(ushort8v*)&As[r * 72 + c8 * 8] = va;
            *(ushort8v*)&Bhs[r * 72 + c8 * 8] =
                *(const ushort8v*)(Bh + (size_t)(col0 + r) * 128 + ks * 64 + c8 * 8);
            *(ushort8v*)&Bls[r * 72 + c8 * 8] =
                *(const ushort8v*)(Bl + (size_t)(col0 + r) * 128 + ks * 64 + c8 * 8);
        }
        __syncthreads();
#pragma unroll
        for (int q = 0; q < 2; ++q) {
            int ko = q * 32 + lq * 8;
            f16x8 av[2], bh[2], bl[2];
#pragma unroll
            for (int i = 0; i < 2; ++i)
                av[i] = *(const f16x8*)&As[(wm + i * 16 + lm) * 72 + ko];
#pragma unroll
            for (int j = 0; j < 2; ++j) {
                bh[j] = *(const f16x8*)&Bhs[(wn + j * 16 + lm) * 72 + ko];
                bl[j] = *(const f16x8*)&Bls[(wn + j * 16 + lm) * 72 + ko];
            }
#pragma unroll
            for (int i = 0; i < 2; ++i)
#pragma unroll
                for (int j = 0; j < 2; ++j) {
                    acc[i][j] = __builtin_amdgcn_mfma_f32_16x16x32_f16(av[i], bh[j], acc[i][j], 0, 0, 0);
                    acc[i][j] = __builtin_amdgcn_mfma_f32_16x16x32_f16(av[i], bl[j], acc[i][j], 0, 0, 0);
                }
        }
    }
#pragma unroll
    for (int i = 0; i < 2; ++i)
#pragma unroll
        for (int reg = 0; reg < 4; ++reg) {
            int gr = row0 + wm + i * 16 + lq * 4 + reg;
            if (gr < M) {
                float sc = rowscale ? rowscale[gr] : 1.0f;
#pragma unroll
                for (int j = 0; j < 2; ++j) {
                    int col = col0 + wn + j * 16 + lm;
                    float v = acc[i][j][reg];
                    if (rowscale) v *= sc;
                    v += bias[col];
                    if (relu) v = fmaxf(v, 0.f);
                    if (postscale) v *= sc;
                    out[(size_t)gr * NC + col] = (_Float16)v;
                }
            }
        }
}

// ---------------- fully-fused GRU: 64-node blocks, no spills ----------------
// 512 threads = 8 waves; wave w owns h-cols [16w,16w+16), all 64 rows (i in [0,4)).
// h kept in LDS as PACKED (fp16 hi | fp16 lo)<<16 u32 -> split computed once at
// write, consumed 8x at read. F fragments read directly from global (L1/L2-hot).
// XOR swizzle (byte ^= (row&7)<<4) kills the 8-way bank conflict of the
// strided fragment reads. acc regs: 4 gates x 4 i x f32x4 = 64 VGPR -> fits
// launch_bounds(512,4) cap of 128, 2 blocks/CU.
__global__ __launch_bounds__(512, 4) void gru_all_k(const _Float16* __restrict__ F,
                                                    const _Float16* __restrict__ wihh,
                                                    const _Float16* __restrict__ wihl,
                                                    const _Float16* __restrict__ whhh,
                                                    const _Float16* __restrict__ whhl,
                                                    const float* __restrict__ b_ih,
                                                    const float* __restrict__ b_hh,
                                                    float* __restrict__ hgru) {
    __shared__ unsigned hs2[64 * 132];
    int t = threadIdx.x;
    int row0 = blockIdx.x * 64;
    for (int s = t; s < 64 * 132; s += 512) hs2[s] = 0u;

    int w = t >> 6, lane = t & 63;
    int lm = lane & 15, lq = lane >> 4;
    int h_idx = w * 16 + lm;
    float bsr = b_ih[h_idx] + b_hh[h_idx];
    float bsz = b_ih[h_idx + 128] + b_hh[h_idx + 128];
    float bni = b_ih[h_idx + 256];
    float bnh = b_hh[h_idx + 256];
    size_t wbase = (size_t)h_idx * 128 + lq * 8;
    const _Float16* Fb = F + (size_t)(row0 + lm) * 128 + lq * 8;
    bool rowok[4];
#pragma unroll
    for (int i = 0; i < 4; ++i) rowok[i] = (row0 + i * 16 + lm) < NN;

    char* hsb = (char*)hs2;

    for (int tt = 0; tt < TT; ++tt) {
        __syncthreads();
        const _Float16* Ft = Fb + (size_t)tt * NN * 128;

        f32x4 accr[4], accz[4], accni[4], accnh[4];
#pragma unroll
        for (int i = 0; i < 4; ++i) {
            accr[i] = (f32x4){0.f, 0.f, 0.f, 0.f};
            accz[i] = (f32x4){0.f, 0.f, 0.f, 0.f};
            accni[i] = (f32x4){0.f, 0.f, 0.f, 0.f};
            accnh[i] = (f32x4){0.f, 0.f, 0.f, 0.f};
        }

        // ---- ih: gi = F_t @ wih^T (A exact fp16, 2-term B split) ----
#pragma unroll
        for (int q = 0; q < 4; ++q) {
            size_t o = wbase + q * 32;
            f16x8 wr_h = *(const f16x8*)(wihh + o);
            f16x8 wr_l = *(const f16x8*)(wihl + o);
            f16x8 wz_h = *(const f16x8*)(wihh + o + 16384);
            f16x8 wz_l = *(const f16x8*)(wihl + o + 16384);
            f16x8 wn_h = *(const f16x8*)(wihh + o + 32768);
            f16x8 wn_l = *(const f16x8*)(wihl + o + 32768);
            f16x8 af[4];
#pragma unroll
            for (int i = 0; i < 4; ++i)
                af[i] = rowok[i] ? *(const f16x8*)(Ft + (size_t)i * 2048 + q * 32)
                                 : (f16x8){};
#pragma unroll
            for (int i = 0; i < 4; ++i) {
                accr[i]  = __builtin_amdgcn_mfma_f32_16x16x32_f16(af[i], wr_h, accr[i], 0, 0, 0);
                accr[i]  = __builtin_amdgcn_mfma_f32_16x16x32_f16(af[i], wr_l, accr[i], 0, 0, 0);
                accz[i]  = __builtin_amdgcn_mfma_f32_16x16x32_f16(af[i], wz_h, accz[i], 0, 0, 0);
                accz[i]  = __builtin_amdgcn_mfma_f32_16x16x32_f16(af[i], wz_l, accz[i], 0, 0, 0);
                accni[i] = __builtin_amdgcn_mfma_f32_16x16x32_f16(af[i], wn_h, accni[i], 0, 0, 0);
                accni[i] = __builtin_amdgcn_mfma_f32_16x16x32_f16(af[i], wn_l, accni[i], 0, 0, 0);
            }
        }

        // ---- hh: gh = h @ whh^T (A = packed hi/lo from LDS, 3 terms) ----
#pragma unroll
        for (int q = 0; q < 4; ++q) {
            size_t o = wbase + q * 32;
            f16x8 wr_h = *(const f16x8*)(whhh + o);
            f16x8 wr_l = *(const f16x8*)(whhl + o);
            f16x8 wz_h = *(const f16x8*)(whhh + o + 16384);
            f16x8 wz_l = *(const f16x8*)(whhl + o + 16384);
            f16x8 wn_h = *(const f16x8*)(whhh + o + 32768);
            f16x8 wn_l = *(const f16x8*)(whhl + o + 32768);
#pragma unroll
            for (int i = 0; i < 4; ++i) {
                int row = i * 16 + lm;
                int c0 = (q * 32 + lq * 8) * 4;
                int c1 = c0 + 16;
                int sw = (row & 7) << 4;
                u32x4 v0 = *(const u32x4*)(hsb + row * 528 + (c0 ^ sw));
                u32x4 v1 = *(const u32x4*)(hsb + row * 528 + (c1 ^ sw));
                f16x8 ah, al;
#pragma unroll
                for (int e = 0; e < 4; ++e) {
                    pk16 c; c.u = v0[e]; ah[e] = c.h[0]; al[e] = c.h[1];
                    pk16 d; d.u = v1[e]; ah[e + 4] = d.h[0]; al[e + 4] = d.h[1];
                }
                accr[i]  = __builtin_amdgcn_mfma_f32_16x16x32_f16(ah, wr_h, accr[i], 0, 0, 0);
                accr[i]  = __builtin_amdgcn_mfma_f32_16x16x32_f16(ah, wr_l, accr[i], 0, 0, 0);
                accr[i]  = __builtin_amdgcn_mfma_f32_16x16x32_f16(al, wr_h, accr[i], 0, 0, 0);
                accz[i]  = __builtin_amdgcn_mfma_f32_16x16x32_f16(ah, wz_h, accz[i], 0, 0, 0);
                accz[i]  = __builtin_amdgcn_mfma_f32_16x16x32_f16(ah, wz_l, accz[i], 0, 0, 0);
                accz[i]  = __builtin_amdgcn_mfma_f32_16x16x32_f16(al, wz_h, accz[i], 0, 0, 0);
                accnh[i] = __builtin_amdgcn_mfma_f32_16x16x32_f16(ah, wn_h, accnh[i], 0, 0, 0);
                accnh[i] = __builtin_amdgcn_mfma_f32_16x16x32_f16(ah, wn_l, accnh[i], 0, 0, 0);
                accnh[i] = __builtin_amdgcn_mfma_f32_16x16x32_f16(al, wn_h, accnh[i], 0, 0, 0);
            }
        }

        // ---- gates (reads only own hs2 slot; result overwrites accr) ----
#pragma unroll
        for (int i = 0; i < 4; ++i)
#pragma unroll
            for (int reg = 0; reg < 4; ++reg) {
                int row_l = i * 16 + lq * 4 + reg;
                pk16 c;
                c.u = *(const unsigned*)(hsb + row_l * 528 + ((h_idx * 4) ^ ((row_l & 7) << 4)));
                float hp = (float)c.h[0] + (float)c.h[1];
                float r = 1.f / (1.f + __expf(-(accr[i][reg] + bsr)));
                float z = 1.f / (1.f + __expf(-(accz[i][reg] + bsz)));
                float nv = tanhf(accni[i][reg] + bni + r * (accnh[i][reg] + bnh));
                accr[i][reg] = (1.f - z) * nv + z * hp;
            }
        __syncthreads();
#pragma unroll
        for (int i = 0; i < 4; ++i)
#pragma unroll
            for (int reg = 0; reg < 4; ++reg) {
                int row_l = i * 16 + lq * 4 + reg;
                float hv = accr[i][reg];
                _Float16 hi = (_Float16)hv;
                pk16 c; c.h[0] = hi; c.h[1] = (_Float16)(hv - (float)hi);
                *(unsigned*)(hsb + row_l * 528 + ((h_idx * 4) ^ ((row_l & 7) << 4))) = c.u;
                if (tt == TT - 1 && row0 + row_l < NN)
                    hgru[(size_t)(row0 + row_l) * 128 + h_idx] = hv;
            }
    }
}

// ---------------- decode ----------------
__global__ __launch_bounds__(256) void decode_k(const float* __restrict__ hgru,
                                                const int* __restrict__ pairs,
                                                float* __restrict__ out) {
    int gid = blockIdx.x * blockDim.x + threadIdx.x;
    int w = gid >> 6;
    int lane = threadIdx.x & 63;
    if (w >= PP) return;
    int s = pairs[w], d = pairs[PP + w];
    const float* zs = hgru + (size_t)s * HH;
    const float* zd = hgru + (size_t)d * HH;
    float acc = zs[lane] * zd[lane] + zs[lane + 64] * zd[lane + 64];
#pragma unroll
    for (int off = 32; off > 0; off >>= 1) acc += __shfl_down(acc, off);
    if (lane == 0) out[w] = acc;
}

// ---------------- orchestration ----------------
static inline size_t align256(size_t x) { return (x + 255) & ~(size_t)255; }

extern "C" void kernel_launch(void* const* d_in, const int* in_sizes, int n_in,
                              void* d_out, int out_size, void* d_ws, size_t ws_size,
                              hipStream_t stream) {
    const float* x_seq      = (const float*)d_in[0];
    const int*   edge_index = (const int*)d_in[1];
    const int*   edge_pairs = (const int*)d_in[2];
    const float* W1 = (const float*)d_in[3];
    const float* b1 = (const float*)d_in[4];
    const float* W2 = (const float*)d_in[5];
    const float* b2 = (const float*)d_in[6];
    const float* W3 = (const float*)d_in[7];
    const float* b3 = (const float*)d_in[8];
    const float* w_ih = (const float*)d_in[9];
    const float* w_hh = (const float*)d_in[10];
    const float* b_ih = (const float*)d_in[11];
    const float* b_hh = (const float*)d_in[12];

    const size_t MALL = (size_t)TT * NN;   // 320000

    char* p = (char*)d_ws;
    int*   cnt_all    = (int*)p;   p += align256(MALL * sizeof(int));
    int*   offs_all   = (int*)p;   p += align256((size_t)TT * (NN + 1) * sizeof(int));
    int*   cursor_all = (int*)p;   p += align256(MALL * sizeof(int));
    float* dinv_all   = (float*)p; p += align256(MALL * sizeof(float));
    unsigned short* csr_all = (unsigned short*)p; p += align256((size_t)TT * EE * sizeof(unsigned short));
    _Float16* g   = (_Float16*)p;  p += align256(MALL * HH * sizeof(_Float16));
    _Float16* a   = (_Float16*)p;  p += align256(MALL * HH * sizeof(_Float16));
    _Float16* F   = (_Float16*)p;  p += align256(MALL * HH * sizeof(_Float16));
    float* hgru = (float*)p;       p += align256((size_t)NN * HH * sizeof(float));
    _Float16* W1h = (_Float16*)p; p += align256(128 * 128 * 2);
    _Float16* W1l = (_Float16*)p; p += align256(128 * 128 * 2);
    _Float16* W2h = (_Float16*)p; p += align256(128 * 128 * 2);
    _Float16* W2l = (_Float16*)p; p += align256(128 * 128 * 2);
    _Float16* W3h = (_Float16*)p; p += align256(128 * 128 * 2);
    _Float16* W3l = (_Float16*)p; p += align256(128 * 128 * 2);
    _Float16* wihh = (_Float16*)p; p += align256(384 * 128 * 2);
    _Float16* wihl = (_Float16*)p; p += align256(384 * 128 * 2);
    _Float16* whhh = (_Float16*)p; p += align256(384 * 128 * 2);
    _Float16* whhl = (_Float16*)p; p += align256(384 * 128 * 2);

    hipMemsetAsync(cnt_all, 0, MALL * sizeof(int), stream);

    wprep_t_k<<<64, 256, 0, stream>>>(W1, W1h, W1l);
    wprep_t_k<<<64, 256, 0, stream>>>(W2, W2h, W2l);
    wprep_t_k<<<64, 256, 0, stream>>>(W3, W3h, W3l);
    wprep_d_k<<<192, 256, 0, stream>>>(w_ih, wihh, wihl, 384 * 128);
    wprep_d_k<<<192, 256, 0, stream>>>(w_hh, whhh, whhl, 384 * 128);

    int ge = ((EE + 1023) / 1024) * TT;   // 4 edges/thread
    hist_all_k<<<ge, 256, 0, stream>>>(edge_index, cnt_all);
    scan_all_k<<<TT, 1024, 0, stream>>>(cnt_all, offs_all, dinv_all, cursor_all);
    fill_all_k<<<ge, 256, 0, stream>>>(edge_index, cursor_all, csr_all);

    scale_k<<<(int)(MALL * 32 / 256), 256, 0, stream>>>(x_seq, dinv_all, g);

    int gagg = 8 * QN * 4;                        // xcd * group * (octet,half)
    int ggemm = 2 * (int)(MALL / 64);             // 10000, XCD-bijective decode in-kernel

    agg_half_k<<<gagg, 128, 0, stream>>>(g, csr_all, offs_all, a);
    gemm_f16<<<ggemm, 256, 0, stream>>>(a, W1h, W1l, g, dinv_all, b1, (int)MALL, 128, 1, 1);
    agg_half_k<<<gagg, 128, 0, stream>>>(g, csr_all, offs_all, a);
    gemm_f16<<<ggemm, 256, 0, stream>>>(a, W2h, W2l, g, dinv_all, b2, (int)MALL, 128, 1, 1);
    agg_half_k<<<gagg, 128, 0, stream>>>(g, csr_all, offs_all, a);
    gemm_f16<<<ggemm, 256, 0, stream>>>(a, W3h, W3l, F, dinv_all, b3, (int)MALL, 128, 0, 0);

    int gru_blocks = (NN + 63) / 64;              // 313
    gru_all_k<<<gru_blocks, 512, 0, stream>>>(F, wihh, wihl, whhh, whhl,
                                              b_ih, b_hh, hgru);

    decode_k<<<(PP * 64 + 255) / 256, 256, 0, stream>>>(hgru, edge_pairs, (float*)d_out);
}

// Round 5
// 1925.063 us; speedup vs baseline: 1.0646x; 1.0646x over previous
//
#include <hip/hip_runtime.h>
#include <hip/hip_bf16.h>

#define NN 20000
#define TT 16
#define EE 320000
#define CC 128
#define HH 128
#define PP 100000
#define QN (NN / 4)   // node groups of 4 for agg

typedef float  f32x4  __attribute__((ext_vector_type(4)));
typedef unsigned short ushort8v __attribute__((ext_vector_type(8)));
typedef unsigned u32x4 __attribute__((ext_vector_type(4)));
typedef _Float16 h2v __attribute__((ext_vector_type(2)));
typedef _Float16 h4v __attribute__((ext_vector_type(4)));
typedef _Float16 f16x8 __attribute__((ext_vector_type(8)));

union pk16 { unsigned u; _Float16 h[2]; };

// ---------------- batched CSR build, XCD-pinned: frame = blockIdx.x % 16 ----------------

__global__ void hist_all_k(const int* __restrict__ edge_index, int* __restrict__ cnt_all) {
    int b = blockIdx.x;
    int f = b & 15, chunk = b >> 4;
    const int* dst = edge_index + (size_t)f * 2 * EE + EE;
    int* cnt = cnt_all + f * NN;
    int base = chunk * 1024 + threadIdx.x;
#pragma unroll
    for (int i = 0; i < 4; ++i) {
        int e = base + i * 256;
        if (e < EE) {
            int d = __builtin_nontemporal_load(dst + e);
            atomicAdd(&cnt[d], 1);
        }
    }
}

__global__ __launch_bounds__(1024) void scan_all_k(const int* __restrict__ cnt_all,
                                                   int* __restrict__ offs_all,
                                                   float* __restrict__ dinv_all,
                                                   int* __restrict__ cursor_all) {
    __shared__ int part[1024];
    int f = blockIdx.x;
    const int* cnt = cnt_all + f * NN;
    int* offs = offs_all + f * (NN + 1);
    int t = threadIdx.x;
    int base = t * 20;
    int vals[20];
    int s = 0;
#pragma unroll
    for (int i = 0; i < 20; ++i) {
        int idx = base + i;
        int v = (idx < NN) ? cnt[idx] : 0;
        vals[i] = v; s += v;
    }
    part[t] = s;
    __syncthreads();
    for (int off = 1; off < 1024; off <<= 1) {
        int v = (t >= off) ? part[t - off] : 0;
        __syncthreads();
        part[t] += v;
        __syncthreads();
    }
    int run = part[t] - s;
#pragma unroll
    for (int i = 0; i < 20; ++i) {
        int idx = base + i;
        if (idx < NN) {
            offs[idx] = run;
            cursor_all[f * NN + idx] = f * EE + run;
            dinv_all[f * NN + idx] = rsqrtf((float)vals[i] + 1.0f);
            run += vals[i];
        }
    }
    if (t == 0) offs[NN] = EE;
}

__global__ void fill_all_k(const int* __restrict__ edge_index,
                           int* __restrict__ cursor_all,
                           unsigned short* __restrict__ csr_all) {
    int b = blockIdx.x;
    int f = b & 15, chunk = b >> 4;
    const int* src = edge_index + (size_t)f * 2 * EE;
    const int* dst = src + EE;
    int* cur = cursor_all + f * NN;
    int base = chunk * 1024 + threadIdx.x;
#pragma unroll
    for (int i = 0; i < 4; ++i) {
        int e = base + i * 256;
        if (e < EE) {
            int d = __builtin_nontemporal_load(dst + e);
            int s = __builtin_nontemporal_load(src + e);
            int pos = atomicAdd(&cur[d], 1);
            csr_all[pos] = (unsigned short)s;
        }
    }
}

// ---------------- weight prep: fp32 -> fp16 high + fp16 residual (22-bit coverage) ----------------
__global__ void wprep_t_k(const float* __restrict__ W,
                          _Float16* __restrict__ oh,
                          _Float16* __restrict__ ol) {
    int i = blockIdx.x * blockDim.x + threadIdx.x;
    if (i >= 128 * 128) return;
    int n = i >> 7, k = i & 127;
    float v = W[k * 128 + n];
    _Float16 h = (_Float16)v;
    oh[i] = h;
    ol[i] = (_Float16)(v - (float)h);
}

__global__ void wprep_d_k(const float* __restrict__ w,
                          _Float16* __restrict__ oh,
                          _Float16* __restrict__ ol, int n) {
    int i = blockIdx.x * blockDim.x + threadIdx.x;
    if (i >= n) return;
    float v = w[i];
    _Float16 h = (_Float16)v;
    oh[i] = h;
    ol[i] = (_Float16)(v - (float)h);
}

// ---------------- g0 = dinv ⊙ x  (fp32 -> fp16) ----------------
__global__ __launch_bounds__(256) void scale_k(const float* __restrict__ x,
                                               const float* __restrict__ dinv_all,
                                               _Float16* __restrict__ g) {
    int idx = blockIdx.x * blockDim.x + threadIdx.x;
    int row = idx >> 5, q = idx & 31;
    const f32x4* xp = (const f32x4*)(x + (size_t)row * 128 + q * 4);
    f32x4 v = __builtin_nontemporal_load(xp);
    float d = dinv_all[row];
    h4v o;
    o.x = (_Float16)(v.x * d); o.y = (_Float16)(v.y * d);
    o.z = (_Float16)(v.z * d); o.w = (_Float16)(v.w * d);
    *(h4v*)(g + (size_t)row * 128 + q * 4) = o;
}

// ---------------- aggregation, feature-halved + XCD-pinned ----------------
__global__ __launch_bounds__(128) void agg_half_k(const _Float16* __restrict__ g,
                                                  const unsigned short* __restrict__ csr_all,
                                                  const int* __restrict__ offs_all,
                                                  _Float16* __restrict__ a) {
    int b = blockIdx.x;
    int xcd = b & 7;
    int r1 = b >> 3;
    int grp = r1 % QN;
    int pass = r1 / QN;                 // 0..3, slowest
    int f = xcd + ((pass & 1) << 3);    // frame octet
    int hoff = (pass >> 1) * 64;        // feature half
    int t = threadIdx.x;
    int node = grp * 4 + (t >> 5);
    int lane = t & 31;
    const int* offs = offs_all + f * (NN + 1);
    const unsigned short* csr = csr_all + (size_t)f * EE;
    const _Float16* gf = g + (size_t)f * NN * HH + hoff + lane * 2;
    int beg = offs[node], end = offs[node + 1];
    float a0 = 0.f, a1 = 0.f;
    int e = beg;
    for (; e + 3 < end; e += 4) {
        int s0 = csr[e], s1 = csr[e + 1], s2 = csr[e + 2], s3 = csr[e + 3];
        h2v v0 = *(const h2v*)(gf + (size_t)s0 * HH);
        h2v v1 = *(const h2v*)(gf + (size_t)s1 * HH);
        h2v v2 = *(const h2v*)(gf + (size_t)s2 * HH);
        h2v v3 = *(const h2v*)(gf + (size_t)s3 * HH);
        a0 += ((float)v0.x + (float)v1.x) + ((float)v2.x + (float)v3.x);
        a1 += ((float)v0.y + (float)v1.y) + ((float)v2.y + (float)v3.y);
    }
    for (; e < end; ++e) {
        h2v v = *(const h2v*)(gf + (size_t)csr[e] * HH);
        a0 += (float)v.x; a1 += (float)v.y;
    }
    h2v vs = *(const h2v*)(gf + (size_t)node * HH);
    a0 += (float)vs.x; a1 += (float)vs.y;
    h2v r; r.x = (_Float16)a0; r.y = (_Float16)a1;
    *(h2v*)(a + ((size_t)f * NN + node) * HH + hoff + lane * 2) = r;
}

// ---------------- fp16 MFMA GEMM, XCD-bijective swizzle ----------------
__global__ __launch_bounds__(256) void gemm_f16(const _Float16* __restrict__ A,
                                                const _Float16* __restrict__ Bh,
                                                const _Float16* __restrict__ Bl,
                                                _Float16* __restrict__ out,
                                                const float* __restrict__ rowscale,
                                                const float* __restrict__ bias,
                                                int M, int NC, int relu, int postscale) {
    __shared__ _Float16 As[64 * 72], Bhs[64 * 72], Bls[64 * 72];
    int t = threadIdx.x;
    int b = blockIdx.x;
    int xcd = b & 7, k = b >> 3;
    int row_t = xcd + ((k >> 1) << 3);     // M/64 = 5000 = 8*625, bijective
    int col_t = k & 1;
    int row0 = row_t * 64, col0 = col_t * 64;
    int w = t >> 6, lane = t & 63;
    int wm = (w & 1) * 32, wn = (w >> 1) * 32;
    int lm = lane & 15, lq = lane >> 4;
    f32x4 acc[2][2] = {};

    for (int ks = 0; ks < 2; ++ks) {
        if (ks) __syncthreads();
#pragma unroll
        for (int p = 0; p < 2; ++p) {
            int s = t + p * 256;
            int r = s >> 3, c8 = s & 7;
            int gr = row0 + r;
            ushort8v va = {};
            if (gr < M)
                va = *(const ushort8v*)(A + (size_t)gr * 128 + ks * 64 + c8 * 8);
            *(ushort8v*)&As[r * 72 + c8 * 8] = va;
            *(ushort8v*)&Bhs[r * 72 + c8 * 8] =
                *(const ushort8v*)(Bh + (size_t)(col0 + r) * 128 + ks * 64 + c8 * 8);
            *(ushort8v*)&Bls[r * 72 + c8 * 8] =
                *(const ushort8v*)(Bl + (size_t)(col0 + r) * 128 + ks * 64 + c8 * 8);
        }
        __syncthreads();
#pragma unroll
        for (int q = 0; q < 2; ++q) {
            int ko = q * 32 + lq * 8;
            f16x8 av[2], bh[2], bl[2];
#pragma unroll
            for (int i = 0; i < 2; ++i)
                av[i] = *(const f16x8*)&As[(wm + i * 16 + lm) * 72 + ko];
#pragma unroll
            for (int j = 0; j < 2; ++j) {
                bh[j] = *(const f16x8*)&Bhs[(wn + j * 16 + lm) * 72 + ko];
                bl[j] = *(const f16x8*)&Bls[(wn + j * 16 + lm) * 72 + ko];
            }
#pragma unroll
            for (int i = 0; i < 2; ++i)
#pragma unroll
                for (int j = 0; j < 2; ++j) {
                    acc[i][j] = __builtin_amdgcn_mfma_f32_16x16x32_f16(av[i], bh[j], acc[i][j], 0, 0, 0);
                    acc[i][j] = __builtin_amdgcn_mfma_f32_16x16x32_f16(av[i], bl[j], acc[i][j], 0, 0, 0);
                }
        }
    }
#pragma unroll
    for (int i = 0; i < 2; ++i)
#pragma unroll
        for (int reg = 0; reg < 4; ++reg) {
            int gr = row0 + wm + i * 16 + lq * 4 + reg;
            if (gr < M) {
                float sc = rowscale ? rowscale[gr] : 1.0f;
#pragma unroll
                for (int j = 0; j < 2; ++j) {
                    int col = col0 + wn + j * 16 + lm;
                    float v = acc[i][j][reg];
                    if (rowscale) v *= sc;
                    v += bias[col];
                    if (relu) v = fmaxf(v, 0.f);
                    if (postscale) v *= sc;
                    out[(size_t)gr * NC + col] = (_Float16)v;
                }
            }
        }
}

// ---------------- fully-fused GRU: 64-node blocks ----------------
// 512 threads = 8 waves; wave w owns h-cols [16w,16w+16), all 64 rows (i in [0,4)).
// h kept in LDS as PACKED (fp16 hi | fp16 lo) u32. F fragments read directly
// from global (L1/L2-hot). XOR swizzle on hs.
// launch_bounds(512, 1): VGPR cap = 131072/(1*512) = 256. Round-4's (512,4)
// capped VGPRs at 64 -> total accumulator spill (1.2 GB phantom traffic).
// Accs (64) + weight frags (24) + F frags (16) + addressing fit in ~150.
__global__ __launch_bounds__(512, 1) void gru_all_k(const _Float16* __restrict__ F,
                                                    const _Float16* __restrict__ wihh,
                                                    const _Float16* __restrict__ wihl,
                                                    const _Float16* __restrict__ whhh,
                                                    const _Float16* __restrict__ whhl,
                                                    const float* __restrict__ b_ih,
                                                    const float* __restrict__ b_hh,
                                                    float* __restrict__ hgru) {
    __shared__ unsigned hs2[64 * 132];
    int t = threadIdx.x;
    int row0 = blockIdx.x * 64;
    for (int s = t; s < 64 * 132; s += 512) hs2[s] = 0u;

    int w = t >> 6, lane = t & 63;
    int lm = lane & 15, lq = lane >> 4;
    int h_idx = w * 16 + lm;
    float bsr = b_ih[h_idx] + b_hh[h_idx];
    float bsz = b_ih[h_idx + 128] + b_hh[h_idx + 128];
    float bni = b_ih[h_idx + 256];
    float bnh = b_hh[h_idx + 256];
    size_t wbase = (size_t)h_idx * 128 + lq * 8;
    const _Float16* Fb = F + (size_t)(row0 + lm) * 128 + lq * 8;
    bool rowok[4];
#pragma unroll
    for (int i = 0; i < 4; ++i) rowok[i] = (row0 + i * 16 + lm) < NN;

    char* hsb = (char*)hs2;

    for (int tt = 0; tt < TT; ++tt) {
        __syncthreads();
        const _Float16* Ft = Fb + (size_t)tt * NN * 128;

        f32x4 accr[4], accz[4], accni[4], accnh[4];
#pragma unroll
        for (int i = 0; i < 4; ++i) {
            accr[i] = (f32x4){0.f, 0.f, 0.f, 0.f};
            accz[i] = (f32x4){0.f, 0.f, 0.f, 0.f};
            accni[i] = (f32x4){0.f, 0.f, 0.f, 0.f};
            accnh[i] = (f32x4){0.f, 0.f, 0.f, 0.f};
        }

        // ---- ih: gi = F_t @ wih^T (A exact fp16, 2-term B split) ----
#pragma unroll
        for (int q = 0; q < 4; ++q) {
            size_t o = wbase + q * 32;
            f16x8 wr_h = *(const f16x8*)(wihh + o);
            f16x8 wr_l = *(const f16x8*)(wihl + o);
            f16x8 wz_h = *(const f16x8*)(wihh + o + 16384);
            f16x8 wz_l = *(const f16x8*)(wihl + o + 16384);
            f16x8 wn_h = *(const f16x8*)(wihh + o + 32768);
            f16x8 wn_l = *(const f16x8*)(wihl + o + 32768);
            f16x8 af[4];
#pragma unroll
            for (int i = 0; i < 4; ++i)
                af[i] = rowok[i] ? *(const f16x8*)(Ft + (size_t)i * 2048 + q * 32)
                                 : (f16x8){};
#pragma unroll
            for (int i = 0; i < 4; ++i) {
                accr[i]  = __builtin_amdgcn_mfma_f32_16x16x32_f16(af[i], wr_h, accr[i], 0, 0, 0);
                accr[i]  = __builtin_amdgcn_mfma_f32_16x16x32_f16(af[i], wr_l, accr[i], 0, 0, 0);
                accz[i]  = __builtin_amdgcn_mfma_f32_16x16x32_f16(af[i], wz_h, accz[i], 0, 0, 0);
                accz[i]  = __builtin_amdgcn_mfma_f32_16x16x32_f16(af[i], wz_l, accz[i], 0, 0, 0);
                accni[i] = __builtin_amdgcn_mfma_f32_16x16x32_f16(af[i], wn_h, accni[i], 0, 0, 0);
                accni[i] = __builtin_amdgcn_mfma_f32_16x16x32_f16(af[i], wn_l, accni[i], 0, 0, 0);
            }
        }

        // ---- hh: gh = h @ whh^T (A = packed hi/lo from LDS, 3 terms) ----
#pragma unroll
        for (int q = 0; q < 4; ++q) {
            size_t o = wbase + q * 32;
            f16x8 wr_h = *(const f16x8*)(whhh + o);
            f16x8 wr_l = *(const f16x8*)(whhl + o);
            f16x8 wz_h = *(const f16x8*)(whhh + o + 16384);
            f16x8 wz_l = *(const f16x8*)(whhl + o + 16384);
            f16x8 wn_h = *(const f16x8*)(whhh + o + 32768);
            f16x8 wn_l = *(const f16x8*)(whhl + o + 32768);
#pragma unroll
            for (int i = 0; i < 4; ++i) {
                int row = i * 16 + lm;
                int c0 = (q * 32 + lq * 8) * 4;
                int c1 = c0 + 16;
                int sw = (row & 7) << 4;
                u32x4 v0 = *(const u32x4*)(hsb + row * 528 + (c0 ^ sw));
                u32x4 v1 = *(const u32x4*)(hsb + row * 528 + (c1 ^ sw));
                f16x8 ah, al;
#pragma unroll
                for (int e = 0; e < 4; ++e) {
                    pk16 c; c.u = v0[e]; ah[e] = c.h[0]; al[e] = c.h[1];
                    pk16 d; d.u = v1[e]; ah[e + 4] = d.h[0]; al[e + 4] = d.h[1];
                }
                accr[i]  = __builtin_amdgcn_mfma_f32_16x16x32_f16(ah, wr_h, accr[i], 0, 0, 0);
                accr[i]  = __builtin_amdgcn_mfma_f32_16x16x32_f16(ah, wr_l, accr[i], 0, 0, 0);
                accr[i]  = __builtin_amdgcn_mfma_f32_16x16x32_f16(al, wr_h, accr[i], 0, 0, 0);
                accz[i]  = __builtin_amdgcn_mfma_f32_16x16x32_f16(ah, wz_h, accz[i], 0, 0, 0);
                accz[i]  = __builtin_amdgcn_mfma_f32_16x16x32_f16(ah, wz_l, accz[i], 0, 0, 0);
                accz[i]  = __builtin_amdgcn_mfma_f32_16x16x32_f16(al, wz_h, accz[i], 0, 0, 0);
                accnh[i] = __builtin_amdgcn_mfma_f32_16x16x32_f16(ah, wn_h, accnh[i], 0, 0, 0);
                accnh[i] = __builtin_amdgcn_mfma_f32_16x16x32_f16(ah, wn_l, accnh[i], 0, 0, 0);
                accnh[i] = __builtin_amdgcn_mfma_f32_16x16x32_f16(al, wn_h, accnh[i], 0, 0, 0);
            }
        }

        // ---- gates (reads only own hs2 slot; result overwrites accr) ----
#pragma unroll
        for (int i = 0; i < 4; ++i)
#pragma unroll
            for (int reg = 0; reg < 4; ++reg) {
                int row_l = i * 16 + lq * 4 + reg;
                pk16 c;
                c.u = *(const unsigned*)(hsb + row_l * 528 + ((h_idx * 4) ^ ((row_l & 7) << 4)));
                float hp = (float)c.h[0] + (float)c.h[1];
                float r = 1.f / (1.f + __expf(-(accr[i][reg] + bsr)));
                float z = 1.f / (1.f + __expf(-(accz[i][reg] + bsz)));
                float nv = tanhf(accni[i][reg] + bni + r * (accnh[i][reg] + bnh));
                accr[i][reg] = (1.f - z) * nv + z * hp;
            }
        __syncthreads();
#pragma unroll
        for (int i = 0; i < 4; ++i)
#pragma unroll
            for (int reg = 0; reg < 4; ++reg) {
                int row_l = i * 16 + lq * 4 + reg;
                float hv = accr[i][reg];
                _Float16 hi = (_Float16)hv;
                pk16 c; c.h[0] = hi; c.h[1] = (_Float16)(hv - (float)hi);
                *(unsigned*)(hsb + row_l * 528 + ((h_idx * 4) ^ ((row_l & 7) << 4))) = c.u;
                if (tt == TT - 1 && row0 + row_l < NN)
                    hgru[(size_t)(row0 + row_l) * 128 + h_idx] = hv;
            }
    }
}

// ---------------- decode ----------------
__global__ __launch_bounds__(256) void decode_k(const float* __restrict__ hgru,
                                                const int* __restrict__ pairs,
                                                float* __restrict__ out) {
    int gid = blockIdx.x * blockDim.x + threadIdx.x;
    int w = gid >> 6;
    int lane = threadIdx.x & 63;
    if (w >= PP) return;
    int s = pairs[w], d = pairs[PP + w];
    const float* zs = hgru + (size_t)s * HH;
    const float* zd = hgru + (size_t)d * HH;
    float acc = zs[lane] * zd[lane] + zs[lane + 64] * zd[lane + 64];
#pragma unroll
    for (int off = 32; off > 0; off >>= 1) acc += __shfl_down(acc, off);
    if (lane == 0) out[w] = acc;
}

// ---------------- orchestration ----------------
static inline size_t align256(size_t x) { return (x + 255) & ~(size_t)255; }

extern "C" void kernel_launch(void* const* d_in, const int* in_sizes, int n_in,
                              void* d_out, int out_size, void* d_ws, size_t ws_size,
                              hipStream_t stream) {
    const float* x_seq      = (const float*)d_in[0];
    const int*   edge_index = (const int*)d_in[1];
    const int*   edge_pairs = (const int*)d_in[2];
    const float* W1 = (const float*)d_in[3];
    const float* b1 = (const float*)d_in[4];
    const float* W2 = (const float*)d_in[5];
    const float* b2 = (const float*)d_in[6];
    const float* W3 = (const float*)d_in[7];
    const float* b3 = (const float*)d_in[8];
    const float* w_ih = (const float*)d_in[9];
    const float* w_hh = (const float*)d_in[10];
    const float* b_ih = (const float*)d_in[11];
    const float* b_hh = (const float*)d_in[12];

    const size_t MALL = (size_t)TT * NN;   // 320000

    char* p = (char*)d_ws;
    int*   cnt_all    = (int*)p;   p += align256(MALL * sizeof(int));
    int*   offs_all   = (int*)p;   p += align256((size_t)TT * (NN + 1) * sizeof(int));
    int*   cursor_all = (int*)p;   p += align256(MALL * sizeof(int));
    float* dinv_all   = (float*)p; p += align256(MALL * sizeof(float));
    unsigned short* csr_all = (unsigned short*)p; p += align256((size_t)TT * EE * sizeof(unsigned short));
    _Float16* g   = (_Float16*)p;  p += align256(MALL * HH * sizeof(_Float16));
    _Float16* a   = (_Float16*)p;  p += align256(MALL * HH * sizeof(_Float16));
    _Float16* F   = (_Float16*)p;  p += align256(MALL * HH * sizeof(_Float16));
    float* hgru = (float*)p;       p += align256((size_t)NN * HH * sizeof(float));
    _Float16* W1h = (_Float16*)p; p += align256(128 * 128 * 2);
    _Float16* W1l = (_Float16*)p; p += align256(128 * 128 * 2);
    _Float16* W2h = (_Float16*)p; p += align256(128 * 128 * 2);
    _Float16* W2l = (_Float16*)p; p += align256(128 * 128 * 2);
    _Float16* W3h = (_Float16*)p; p += align256(128 * 128 * 2);
    _Float16* W3l = (_Float16*)p; p += align256(128 * 128 * 2);
    _Float16* wihh = (_Float16*)p; p += align256(384 * 128 * 2);
    _Float16* wihl = (_Float16*)p; p += align256(384 * 128 * 2);
    _Float16* whhh = (_Float16*)p; p += align256(384 * 128 * 2);
    _Float16* whhl = (_Float16*)p; p += align256(384 * 128 * 2);

    hipMemsetAsync(cnt_all, 0, MALL * sizeof(int), stream);

    wprep_t_k<<<64, 256, 0, stream>>>(W1, W1h, W1l);
    wprep_t_k<<<64, 256, 0, stream>>>(W2, W2h, W2l);
    wprep_t_k<<<64, 256, 0, stream>>>(W3, W3h, W3l);
    wprep_d_k<<<192, 256, 0, stream>>>(w_ih, wihh, wihl, 384 * 128);
    wprep_d_k<<<192, 256, 0, stream>>>(w_hh, whhh, whhl, 384 * 128);

    int ge = ((EE + 1023) / 1024) * TT;   // 4 edges/thread
    hist_all_k<<<ge, 256, 0, stream>>>(edge_index, cnt_all);
    scan_all_k<<<TT, 1024, 0, stream>>>(cnt_all, offs_all, dinv_all, cursor_all);
    fill_all_k<<<ge, 256, 0, stream>>>(edge_index, cursor_all, csr_all);

    scale_k<<<(int)(MALL * 32 / 256), 256, 0, stream>>>(x_seq, dinv_all, g);

    int gagg = 8 * QN * 4;                        // xcd * group * (octet,half)
    int ggemm = 2 * (int)(MALL / 64);             // 10000, XCD-bijective decode in-kernel

    agg_half_k<<<gagg, 128, 0, stream>>>(g, csr_all, offs_all, a);
    gemm_f16<<<ggemm, 256, 0, stream>>>(a, W1h, W1l, g, dinv_all, b1, (int)MALL, 128, 1, 1);
    agg_half_k<<<gagg, 128, 0, stream>>>(g, csr_all, offs_all, a);
    gemm_f16<<<ggemm, 256, 0, stream>>>(a, W2h, W2l, g, dinv_all, b2, (int)MALL, 128, 1, 1);
    agg_half_k<<<gagg, 128, 0, stream>>>(g, csr_all, offs_all, a);
    gemm_f16<<<ggemm, 256, 0, stream>>>(a, W3h, W3l, F, dinv_all, b3, (int)MALL, 128, 0, 0);

    int gru_blocks = (NN + 63) / 64;              // 313
    gru_all_k<<<gru_blocks, 512, 0, stream>>>(F, wihh, wihl, whhh, whhl,
                                              b_ih, b_hh, hgru);

    decode_k<<<(PP * 64 + 255) / 256, 256, 0, stream>>>(hgru, edge_pairs, (float*)d_out);
}

// Round 6
// 1728.216 us; speedup vs baseline: 1.1858x; 1.1139x over previous
//
#include <hip/hip_runtime.h>
#include <hip/hip_bf16.h>

#define NN 20000
#define TT 16
#define EE 320000
#define CC 128
#define HH 128
#define PP 100000
#define QN (NN / 4)   // node groups of 4 for agg

typedef float  f32x4  __attribute__((ext_vector_type(4)));
typedef unsigned short ushort8v __attribute__((ext_vector_type(8)));
typedef unsigned u32x4 __attribute__((ext_vector_type(4)));
typedef _Float16 h2v __attribute__((ext_vector_type(2)));
typedef _Float16 h4v __attribute__((ext_vector_type(4)));
typedef _Float16 f16x8 __attribute__((ext_vector_type(8)));

union pk16 { unsigned u; _Float16 h[2]; };

// ---------------- batched CSR build, XCD-pinned: frame = blockIdx.x % 16 ----------------

__global__ void hist_all_k(const int* __restrict__ edge_index, int* __restrict__ cnt_all) {
    int b = blockIdx.x;
    int f = b & 15, chunk = b >> 4;
    const int* dst = edge_index + (size_t)f * 2 * EE + EE;
    int* cnt = cnt_all + f * NN;
    int base = chunk * 1024 + threadIdx.x;
#pragma unroll
    for (int i = 0; i < 4; ++i) {
        int e = base + i * 256;
        if (e < EE) {
            int d = __builtin_nontemporal_load(dst + e);
            atomicAdd(&cnt[d], 1);
        }
    }
}

__global__ __launch_bounds__(1024) void scan_all_k(const int* __restrict__ cnt_all,
                                                   int* __restrict__ offs_all,
                                                   float* __restrict__ dinv_all,
                                                   int* __restrict__ cursor_all) {
    __shared__ int part[1024];
    int f = blockIdx.x;
    const int* cnt = cnt_all + f * NN;
    int* offs = offs_all + f * (NN + 1);
    int t = threadIdx.x;
    int base = t * 20;
    int vals[20];
    int s = 0;
#pragma unroll
    for (int i = 0; i < 20; ++i) {
        int idx = base + i;
        int v = (idx < NN) ? cnt[idx] : 0;
        vals[i] = v; s += v;
    }
    part[t] = s;
    __syncthreads();
    for (int off = 1; off < 1024; off <<= 1) {
        int v = (t >= off) ? part[t - off] : 0;
        __syncthreads();
        part[t] += v;
        __syncthreads();
    }
    int run = part[t] - s;
#pragma unroll
    for (int i = 0; i < 20; ++i) {
        int idx = base + i;
        if (idx < NN) {
            offs[idx] = run;
            cursor_all[f * NN + idx] = f * EE + run;
            dinv_all[f * NN + idx] = rsqrtf((float)vals[i] + 1.0f);
            run += vals[i];
        }
    }
    if (t == 0) offs[NN] = EE;
}

__global__ void fill_all_k(const int* __restrict__ edge_index,
                           int* __restrict__ cursor_all,
                           unsigned short* __restrict__ csr_all) {
    int b = blockIdx.x;
    int f = b & 15, chunk = b >> 4;
    const int* src = edge_index + (size_t)f * 2 * EE;
    const int* dst = src + EE;
    int* cur = cursor_all + f * NN;
    int base = chunk * 1024 + threadIdx.x;
#pragma unroll
    for (int i = 0; i < 4; ++i) {
        int e = base + i * 256;
        if (e < EE) {
            int d = __builtin_nontemporal_load(dst + e);
            int s = __builtin_nontemporal_load(src + e);
            int pos = atomicAdd(&cur[d], 1);
            csr_all[pos] = (unsigned short)s;
        }
    }
}

// ---------------- weight prep ----------------
// GEMM weights (transposed): fp32 -> fp16 hi + fp16 residual, row-major.
__global__ void wprep_t_k(const float* __restrict__ W,
                          _Float16* __restrict__ oh,
                          _Float16* __restrict__ ol) {
    int i = blockIdx.x * blockDim.x + threadIdx.x;
    if (i >= 128 * 128) return;
    int n = i >> 7, k = i & 127;
    float v = W[k * 128 + n];
    _Float16 h = (_Float16)v;
    oh[i] = h;
    ol[i] = (_Float16)(v - (float)h);
}

// GRU weights: split + pack FRAGMENT-MAJOR so every in-kernel fragment load is
// a contiguous 1KB block (lane*16B). unit ((g*8+w)*4+q)*64+lane holds
// W[g*128 + w*16 + (lane&15)][q*32 + (lane>>4)*8 + 0..7].
__global__ __launch_bounds__(256) void wprep_p_k(const float* __restrict__ wsrc,
                                                 _Float16* __restrict__ oh,
                                                 _Float16* __restrict__ ol) {
    int u = blockIdx.x * blockDim.x + threadIdx.x;
    if (u >= 6144) return;
    int lane = u & 63, q = (u >> 6) & 3, wv = (u >> 8) & 7, g = u >> 11;
    int lm = lane & 15, lq = lane >> 4;
    const float* s = wsrc + (size_t)(g * 128 + wv * 16 + lm) * 128 + q * 32 + lq * 8;
#pragma unroll
    for (int e = 0; e < 8; ++e) {
        float v = s[e];
        _Float16 h = (_Float16)v;
        oh[(size_t)u * 8 + e] = h;
        ol[(size_t)u * 8 + e] = (_Float16)(v - (float)h);
    }
}

// ---------------- g0 = dinv ⊙ x  (fp32 -> fp16) ----------------
__global__ __launch_bounds__(256) void scale_k(const float* __restrict__ x,
                                               const float* __restrict__ dinv_all,
                                               _Float16* __restrict__ g) {
    int idx = blockIdx.x * blockDim.x + threadIdx.x;
    int row = idx >> 5, q = idx & 31;
    const f32x4* xp = (const f32x4*)(x + (size_t)row * 128 + q * 4);
    f32x4 v = __builtin_nontemporal_load(xp);
    float d = dinv_all[row];
    h4v o;
    o.x = (_Float16)(v.x * d); o.y = (_Float16)(v.y * d);
    o.z = (_Float16)(v.z * d); o.w = (_Float16)(v.w * d);
    *(h4v*)(g + (size_t)row * 128 + q * 4) = o;
}

// ---------------- aggregation, feature-halved + XCD-pinned ----------------
__global__ __launch_bounds__(128) void agg_half_k(const _Float16* __restrict__ g,
                                                  const unsigned short* __restrict__ csr_all,
                                                  const int* __restrict__ offs_all,
                                                  _Float16* __restrict__ a) {
    int b = blockIdx.x;
    int xcd = b & 7;
    int r1 = b >> 3;
    int grp = r1 % QN;
    int pass = r1 / QN;                 // 0..3, slowest
    int f = xcd + ((pass & 1) << 3);    // frame octet
    int hoff = (pass >> 1) * 64;        // feature half
    int t = threadIdx.x;
    int node = grp * 4 + (t >> 5);
    int lane = t & 31;
    const int* offs = offs_all + f * (NN + 1);
    const unsigned short* csr = csr_all + (size_t)f * EE;
    const _Float16* gf = g + (size_t)f * NN * HH + hoff + lane * 2;
    int beg = offs[node], end = offs[node + 1];
    float a0 = 0.f, a1 = 0.f;
    int e = beg;
    for (; e + 3 < end; e += 4) {
        int s0 = csr[e], s1 = csr[e + 1], s2 = csr[e + 2], s3 = csr[e + 3];
        h2v v0 = *(const h2v*)(gf + (size_t)s0 * HH);
        h2v v1 = *(const h2v*)(gf + (size_t)s1 * HH);
        h2v v2 = *(const h2v*)(gf + (size_t)s2 * HH);
        h2v v3 = *(const h2v*)(gf + (size_t)s3 * HH);
        a0 += ((float)v0.x + (float)v1.x) + ((float)v2.x + (float)v3.x);
        a1 += ((float)v0.y + (float)v1.y) + ((float)v2.y + (float)v3.y);
    }
    for (; e < end; ++e) {
        h2v v = *(const h2v*)(gf + (size_t)csr[e] * HH);
        a0 += (float)v.x; a1 += (float)v.y;
    }
    h2v vs = *(const h2v*)(gf + (size_t)node * HH);
    a0 += (float)vs.x; a1 += (float)vs.y;
    h2v r; r.x = (_Float16)a0; r.y = (_Float16)a1;
    *(h2v*)(a + ((size_t)f * NN + node) * HH + hoff + lane * 2) = r;
}

// ---------------- fp16 MFMA GEMM, XCD-bijective swizzle ----------------
__global__ __launch_bounds__(256) void gemm_f16(const _Float16* __restrict__ A,
                                                const _Float16* __restrict__ Bh,
                                                const _Float16* __restrict__ Bl,
                                                _Float16* __restrict__ out,
                                                const float* __restrict__ rowscale,
                                                const float* __restrict__ bias,
                                                int M, int NC, int relu, int postscale) {
    __shared__ _Float16 As[64 * 72], Bhs[64 * 72], Bls[64 * 72];
    int t = threadIdx.x;
    int b = blockIdx.x;
    int xcd = b & 7, k = b >> 3;
    int row_t = xcd + ((k >> 1) << 3);     // M/64 = 5000 = 8*625, bijective
    int col_t = k & 1;
    int row0 = row_t * 64, col0 = col_t * 64;
    int w = t >> 6, lane = t & 63;
    int wm = (w & 1) * 32, wn = (w >> 1) * 32;
    int lm = lane & 15, lq = lane >> 4;
    f32x4 acc[2][2] = {};

    for (int ks = 0; ks < 2; ++ks) {
        if (ks) __syncthreads();
#pragma unroll
        for (int p = 0; p < 2; ++p) {
            int s = t + p * 256;
            int r = s >> 3, c8 = s & 7;
            int gr = row0 + r;
            ushort8v va = {};
            if (gr < M)
                va = *(const ushort8v*)(A + (size_t)gr * 128 + ks * 64 + c8 * 8);
            *(ushort8v*)&As[r * 72 + c8 * 8] = va;
            *(ushort8v*)&Bhs[r * 72 + c8 * 8] =
                *(const ushort8v*)(Bh + (size_t)(col0 + r) * 128 + ks * 64 + c8 * 8);
            *(ushort8v*)&Bls[r * 72 + c8 * 8] =
                *(const ushort8v*)(Bl + (size_t)(col0 + r) * 128 + ks * 64 + c8 * 8);
        }
        __syncthreads();
#pragma unroll
        for (int q = 0; q < 2; ++q) {
            int ko = q * 32 + lq * 8;
            f16x8 av[2], bh[2], bl[2];
#pragma unroll
            for (int i = 0; i < 2; ++i)
                av[i] = *(const f16x8*)&As[(wm + i * 16 + lm) * 72 + ko];
#pragma unroll
            for (int j = 0; j < 2; ++j) {
                bh[j] = *(const f16x8*)&Bhs[(wn + j * 16 + lm) * 72 + ko];
                bl[j] = *(const f16x8*)&Bls[(wn + j * 16 + lm) * 72 + ko];
            }
#pragma unroll
            for (int i = 0; i < 2; ++i)
#pragma unroll
                for (int j = 0; j < 2; ++j) {
                    acc[i][j] = __builtin_amdgcn_mfma_f32_16x16x32_f16(av[i], bh[j], acc[i][j], 0, 0, 0);
                    acc[i][j] = __builtin_amdgcn_mfma_f32_16x16x32_f16(av[i], bl[j], acc[i][j], 0, 0, 0);
                }
        }
    }
#pragma unroll
    for (int i = 0; i < 2; ++i)
#pragma unroll
        for (int reg = 0; reg < 4; ++reg) {
            int gr = row0 + wm + i * 16 + lq * 4 + reg;
            if (gr < M) {
                float sc = rowscale ? rowscale[gr] : 1.0f;
#pragma unroll
                for (int j = 0; j < 2; ++j) {
                    int col = col0 + wn + j * 16 + lm;
                    float v = acc[i][j][reg];
                    if (rowscale) v *= sc;
                    v += bias[col];
                    if (relu) v = fmaxf(v, 0.f);
                    if (postscale) v *= sc;
                    out[(size_t)gr * NC + col] = (_Float16)v;
                }
            }
        }
}

// ---------------- fully-fused GRU: fragment-major everywhere ----------------
// 64-node blocks, 512 threads (8 waves); wave w owns h-cols [16w,16w+16).
// All hot reads are contiguous base+lane*16B blocks:
//  - weights: packed fragment-major by wprep_p_k -> coalesced 1KB L2 streams
//  - F_t: staged in LDS fragment-major (16KB, shared by all 8 waves) -> conflict-free
//  - hs (h state, packed fp16 hi|lo u32): fragment-major 2KB units -> conflict-free reads
__global__ __launch_bounds__(512, 1) void gru_all_k(const _Float16* __restrict__ F,
                                                    const _Float16* __restrict__ wihh,
                                                    const _Float16* __restrict__ wihl,
                                                    const _Float16* __restrict__ whhh,
                                                    const _Float16* __restrict__ whhl,
                                                    const float* __restrict__ b_ih,
                                                    const float* __restrict__ b_hh,
                                                    float* __restrict__ hgru) {
    __shared__ unsigned hsu[8192];       // 32 KB: frag(i,q)*64+lane -> 8 u32 (8 cols hi|lo)
    __shared__ _Float16 fsu[8192];       // 16 KB: frag(i,q)*64+lane -> 8 halfs
    int t = threadIdx.x;
    int row0 = blockIdx.x * 64;
    for (int s = t; s < 8192; s += 512) hsu[s] = 0u;

    int w = t >> 6, lane = t & 63;
    int lm = lane & 15, lq = lane >> 4;
    int h_idx = w * 16 + lm;
    float bsr = b_ih[h_idx] + b_hh[h_idx];
    float bsz = b_ih[h_idx + 128] + b_hh[h_idx + 128];
    float bni = b_ih[h_idx + 256];
    float bnh = b_hh[h_idx + 256];
    // packed weight base: halfs = ((g*8+w)*4+q)*512 + lane*8
    size_t wb = (size_t)w * 2048 + (size_t)lane * 8;
    // own-column hs coords (gates phase)
    int qv = h_idx >> 5, lqv = (h_idx >> 3) & 3, ev = h_idx & 7;

    for (int tt = 0; tt < TT; ++tt) {
        __syncthreads();
        // ---- stage F_t fragment-major (coalesced global read) ----
        const _Float16* Ft = F + ((size_t)tt * NN + row0) * 128;
#pragma unroll
        for (int it = 0; it < 2; ++it) {
            int s = t + it * 512;            // 0..1023
            int r = s >> 4, c8 = s & 15;
            ushort8v val = {};
            if (row0 + r < NN)
                val = *(const ushort8v*)(Ft + (size_t)r * 128 + c8 * 8);
            int fu = ((r >> 4) * 4 + (c8 >> 2)) * 64 + (c8 & 3) * 16 + (r & 15);
            *(ushort8v*)(fsu + fu * 8) = val;
        }
        __syncthreads();

        f32x4 accr[4], accz[4], accni[4], accnh[4];
#pragma unroll
        for (int i = 0; i < 4; ++i) {
            accr[i] = (f32x4){0.f, 0.f, 0.f, 0.f};
            accz[i] = (f32x4){0.f, 0.f, 0.f, 0.f};
            accni[i] = (f32x4){0.f, 0.f, 0.f, 0.f};
            accnh[i] = (f32x4){0.f, 0.f, 0.f, 0.f};
        }

        // ---- ih: gi = F_t @ wih^T (A exact fp16, 2-term B split) ----
#pragma unroll
        for (int q = 0; q < 4; ++q) {
            size_t o = wb + q * 512;
            f16x8 wr_h = *(const f16x8*)(wihh + o);
            f16x8 wr_l = *(const f16x8*)(wihl + o);
            f16x8 wz_h = *(const f16x8*)(wihh + o + 16384);
            f16x8 wz_l = *(const f16x8*)(wihl + o + 16384);
            f16x8 wn_h = *(const f16x8*)(wihh + o + 32768);
            f16x8 wn_l = *(const f16x8*)(wihl + o + 32768);
#pragma unroll
            for (int i = 0; i < 4; ++i) {
                f16x8 af = *(const f16x8*)(fsu + ((i * 4 + q) * 64 + lane) * 8);
                accr[i]  = __builtin_amdgcn_mfma_f32_16x16x32_f16(af, wr_h, accr[i], 0, 0, 0);
                accr[i]  = __builtin_amdgcn_mfma_f32_16x16x32_f16(af, wr_l, accr[i], 0, 0, 0);
                accz[i]  = __builtin_amdgcn_mfma_f32_16x16x32_f16(af, wz_h, accz[i], 0, 0, 0);
                accz[i]  = __builtin_amdgcn_mfma_f32_16x16x32_f16(af, wz_l, accz[i], 0, 0, 0);
                accni[i] = __builtin_amdgcn_mfma_f32_16x16x32_f16(af, wn_h, accni[i], 0, 0, 0);
                accni[i] = __builtin_amdgcn_mfma_f32_16x16x32_f16(af, wn_l, accni[i], 0, 0, 0);
            }
        }

        // ---- hh: gh = h @ whh^T (A = packed hi/lo from LDS, 3 terms) ----
#pragma unroll
        for (int q = 0; q < 4; ++q) {
            size_t o = wb + q * 512;
            f16x8 wr_h = *(const f16x8*)(whhh + o);
            f16x8 wr_l = *(const f16x8*)(whhl + o);
            f16x8 wz_h = *(const f16x8*)(whhh + o + 16384);
            f16x8 wz_l = *(const f16x8*)(whhl + o + 16384);
            f16x8 wn_h = *(const f16x8*)(whhh + o + 32768);
            f16x8 wn_l = *(const f16x8*)(whhl + o + 32768);
#pragma unroll
            for (int i = 0; i < 4; ++i) {
                const unsigned* hp = hsu + ((i * 4 + q) * 64 + lane) * 8;
                u32x4 v0 = *(const u32x4*)(hp);
                u32x4 v1 = *(const u32x4*)(hp + 4);
                f16x8 ah, al;
#pragma unroll
                for (int e = 0; e < 4; ++e) {
                    pk16 c; c.u = v0[e]; ah[e] = c.h[0]; al[e] = c.h[1];
                    pk16 d; d.u = v1[e]; ah[e + 4] = d.h[0]; al[e + 4] = d.h[1];
                }
                accr[i]  = __builtin_amdgcn_mfma_f32_16x16x32_f16(ah, wr_h, accr[i], 0, 0, 0);
                accr[i]  = __builtin_amdgcn_mfma_f32_16x16x32_f16(ah, wr_l, accr[i], 0, 0, 0);
                accr[i]  = __builtin_amdgcn_mfma_f32_16x16x32_f16(al, wr_h, accr[i], 0, 0, 0);
                accz[i]  = __builtin_amdgcn_mfma_f32_16x16x32_f16(ah, wz_h, accz[i], 0, 0, 0);
                accz[i]  = __builtin_amdgcn_mfma_f32_16x16x32_f16(ah, wz_l, accz[i], 0, 0, 0);
                accz[i]  = __builtin_amdgcn_mfma_f32_16x16x32_f16(al, wz_h, accz[i], 0, 0, 0);
                accnh[i] = __builtin_amdgcn_mfma_f32_16x16x32_f16(ah, wn_h, accnh[i], 0, 0, 0);
                accnh[i] = __builtin_amdgcn_mfma_f32_16x16x32_f16(ah, wn_l, accnh[i], 0, 0, 0);
                accnh[i] = __builtin_amdgcn_mfma_f32_16x16x32_f16(al, wn_h, accnh[i], 0, 0, 0);
            }
        }

        // ---- gates (own column; result overwrites accr) ----
#pragma unroll
        for (int i = 0; i < 4; ++i)
#pragma unroll
            for (int reg = 0; reg < 4; ++reg) {
                int u = (i * 4 + qv) * 64 + lqv * 16 + lq * 4 + reg;
                pk16 c; c.u = hsu[u * 8 + ev];
                float hp = (float)c.h[0] + (float)c.h[1];
                float r = 1.f / (1.f + __expf(-(accr[i][reg] + bsr)));
                float z = 1.f / (1.f + __expf(-(accz[i][reg] + bsz)));
                float nv = tanhf(accni[i][reg] + bni + r * (accnh[i][reg] + bnh));
                accr[i][reg] = (1.f - z) * nv + z * hp;
            }
        __syncthreads();
#pragma unroll
        for (int i = 0; i < 4; ++i)
#pragma unroll
            for (int reg = 0; reg < 4; ++reg) {
                int u = (i * 4 + qv) * 64 + lqv * 16 + lq * 4 + reg;
                float hv = accr[i][reg];
                _Float16 hi = (_Float16)hv;
                pk16 c; c.h[0] = hi; c.h[1] = (_Float16)(hv - (float)hi);
                hsu[u * 8 + ev] = c.u;
                if (tt == TT - 1) {
                    int gr = row0 + i * 16 + lq * 4 + reg;
                    if (gr < NN) hgru[(size_t)gr * 128 + h_idx] = hv;
                }
            }
    }
}

// ---------------- decode ----------------
__global__ __launch_bounds__(256) void decode_k(const float* __restrict__ hgru,
                                                const int* __restrict__ pairs,
                                                float* __restrict__ out) {
    int gid = blockIdx.x * blockDim.x + threadIdx.x;
    int w = gid >> 6;
    int lane = threadIdx.x & 63;
    if (w >= PP) return;
    int s = pairs[w], d = pairs[PP + w];
    const float* zs = hgru + (size_t)s * HH;
    const float* zd = hgru + (size_t)d * HH;
    float acc = zs[lane] * zd[lane] + zs[lane + 64] * zd[lane + 64];
#pragma unroll
    for (int off = 32; off > 0; off >>= 1) acc += __shfl_down(acc, off);
    if (lane == 0) out[w] = acc;
}

// ---------------- orchestration ----------------
static inline size_t align256(size_t x) { return (x + 255) & ~(size_t)255; }

extern "C" void kernel_launch(void* const* d_in, const int* in_sizes, int n_in,
                              void* d_out, int out_size, void* d_ws, size_t ws_size,
                              hipStream_t stream) {
    const float* x_seq      = (const float*)d_in[0];
    const int*   edge_index = (const int*)d_in[1];
    const int*   edge_pairs = (const int*)d_in[2];
    const float* W1 = (const float*)d_in[3];
    const float* b1 = (const float*)d_in[4];
    const float* W2 = (const float*)d_in[5];
    const float* b2 = (const float*)d_in[6];
    const float* W3 = (const float*)d_in[7];
    const float* b3 = (const float*)d_in[8];
    const float* w_ih = (const float*)d_in[9];
    const float* w_hh = (const float*)d_in[10];
    const float* b_ih = (const float*)d_in[11];
    const float* b_hh = (const float*)d_in[12];

    const size_t MALL = (size_t)TT * NN;   // 320000

    char* p = (char*)d_ws;
    int*   cnt_all    = (int*)p;   p += align256(MALL * sizeof(int));
    int*   offs_all   = (int*)p;   p += align256((size_t)TT * (NN + 1) * sizeof(int));
    int*   cursor_all = (int*)p;   p += align256(MALL * sizeof(int));
    float* dinv_all   = (float*)p; p += align256(MALL * sizeof(float));
    unsigned short* csr_all = (unsigned short*)p; p += align256((size_t)TT * EE * sizeof(unsigned short));
    _Float16* g   = (_Float16*)p;  p += align256(MALL * HH * sizeof(_Float16));
    _Float16* a   = (_Float16*)p;  p += align256(MALL * HH * sizeof(_Float16));
    _Float16* F   = (_Float16*)p;  p += align256(MALL * HH * sizeof(_Float16));
    float* hgru = (float*)p;       p += align256((size_t)NN * HH * sizeof(float));
    _Float16* W1h = (_Float16*)p; p += align256(128 * 128 * 2);
    _Float16* W1l = (_Float16*)p; p += align256(128 * 128 * 2);
    _Float16* W2h = (_Float16*)p; p += align256(128 * 128 * 2);
    _Float16* W2l = (_Float16*)p; p += align256(128 * 128 * 2);
    _Float16* W3h = (_Float16*)p; p += align256(128 * 128 * 2);
    _Float16* W3l = (_Float16*)p; p += align256(128 * 128 * 2);
    _Float16* wihh = (_Float16*)p; p += align256(384 * 128 * 2);
    _Float16* wihl = (_Float16*)p; p += align256(384 * 128 * 2);
    _Float16* whhh = (_Float16*)p; p += align256(384 * 128 * 2);
    _Float16* whhl = (_Float16*)p; p += align256(384 * 128 * 2);

    hipMemsetAsync(cnt_all, 0, MALL * sizeof(int), stream);

    wprep_t_k<<<64, 256, 0, stream>>>(W1, W1h, W1l);
    wprep_t_k<<<64, 256, 0, stream>>>(W2, W2h, W2l);
    wprep_t_k<<<64, 256, 0, stream>>>(W3, W3h, W3l);
    wprep_p_k<<<24, 256, 0, stream>>>(w_ih, wihh, wihl);
    wprep_p_k<<<24, 256, 0, stream>>>(w_hh, whhh, whhl);

    int ge = ((EE + 1023) / 1024) * TT;   // 4 edges/thread
    hist_all_k<<<ge, 256, 0, stream>>>(edge_index, cnt_all);
    scan_all_k<<<TT, 1024, 0, stream>>>(cnt_all, offs_all, dinv_all, cursor_all);
    fill_all_k<<<ge, 256, 0, stream>>>(edge_index, cursor_all, csr_all);

    scale_k<<<(int)(MALL * 32 / 256), 256, 0, stream>>>(x_seq, dinv_all, g);

    int gagg = 8 * QN * 4;                        // xcd * group * (octet,half)
    int ggemm = 2 * (int)(MALL / 64);             // 10000, XCD-bijective decode in-kernel

    agg_half_k<<<gagg, 128, 0, stream>>>(g, csr_all, offs_all, a);
    gemm_f16<<<ggemm, 256, 0, stream>>>(a, W1h, W1l, g, dinv_all, b1, (int)MALL, 128, 1, 1);
    agg_half_k<<<gagg, 128, 0, stream>>>(g, csr_all, offs_all, a);
    gemm_f16<<<ggemm, 256, 0, stream>>>(a, W2h, W2l, g, dinv_all, b2, (int)MALL, 128, 1, 1);
    agg_half_k<<<gagg, 128, 0, stream>>>(g, csr_all, offs_all, a);
    gemm_f16<<<ggemm, 256, 0, stream>>>(a, W3h, W3l, F, dinv_all, b3, (int)MALL, 128, 0, 0);

    int gru_blocks = (NN + 63) / 64;              // 313
    gru_all_k<<<gru_blocks, 512, 0, stream>>>(F, wihh, wihl, whhh, whhl,
                                              b_ih, b_hh, hgru);

    decode_k<<<(PP * 64 + 255) / 256, 256, 0, stream>>>(hgru, edge_pairs, (float*)d_out);
}